// Round 1
// baseline (308.761 us; speedup 1.0000x reference)
//
#include <hip/hip_runtime.h>
#include <math.h>

#define D 128
#define H 64
#define W 100
#define R 20
#define NB 256
#define NDOC_UI (NB * R)   // 5120

// ---------------- Kernel A: tanh-self-attention doc embedding ----------------
// One block (256 threads) per document. Stage 100 emb rows (pad stride 129 ->
// conflict-free LDS), compute per-word scores, softmax over words, weighted sum.
__global__ __launch_bounds__(256) void doc_embed_kernel(
    const int* __restrict__ user_w, const int* __restrict__ item_w,
    const int* __restrict__ query_w,
    const float* __restrict__ emb, const float* __restrict__ w_self,
    const float* __restrict__ b_self,
    float* __restrict__ user_emb, float* __restrict__ item_emb,
    float* __restrict__ q_emb)
{
    __shared__ float lds_we[W * 129];   // 51.6 KB, stride 129 -> bank (w+k)%32
    __shared__ float lds_ws[D];
    __shared__ float lds_sc[W];
    __shared__ int   lds_words[W];
    __shared__ float lds_part[256];

    int doc = blockIdx.x;
    const int* wp; float* outp;
    if (doc < NDOC_UI)          { wp = user_w  + doc * W;              outp = user_emb + doc * D; }
    else if (doc < 2*NDOC_UI)   { int t = doc - NDOC_UI;   wp = item_w  + t * W; outp = item_emb + t * D; }
    else                        { int t = doc - 2*NDOC_UI; wp = query_w + t * W; outp = q_emb    + t * D; }

    int tid = threadIdx.x;
    if (tid < W) lds_words[tid] = wp[tid];
    if (tid < D) lds_ws[tid]    = w_self[tid];
    __syncthreads();

    // Stage 100 rows: 2 rows per iteration, 128 lanes per row (coalesced 512B/row)
    int d    = tid & 127;
    int half = tid >> 7;
    for (int i = 0; i < W / 2; ++i) {
        int w    = i * 2 + half;
        int word = lds_words[w];
        lds_we[w * 129 + d] = emb[(long)word * D + d];
    }
    __syncthreads();

    // Scores: threads 0..99, conflict-free stride-129 rows, w_self broadcast
    float bs = b_self[0];
    if (tid < W) {
        float s = 0.f;
        const float* row = &lds_we[tid * 129];
        #pragma unroll 16
        for (int k = 0; k < D; ++k) s += row[k] * lds_ws[k];
        lds_sc[tid] = tanhf(s + bs);
    }
    __syncthreads();

    // Redundant softmax stats (100 broadcast LDS reads; cheap)
    float m = -1e30f;
    for (int w = 0; w < W; ++w) m = fmaxf(m, lds_sc[w]);
    float sum = 0.f;
    for (int w = 0; w < W; ++w) sum += expf(lds_sc[w] - m);
    float inv = 1.f / sum;

    // Weighted sum: each half of the block handles 50 words for its dim d
    float acc = 0.f;
    for (int w = half * 50; w < half * 50 + 50; ++w) {
        float wt = expf(lds_sc[w] - m) * inv;
        acc += wt * lds_we[w * 129 + d];
    }
    lds_part[tid] = acc;
    __syncthreads();
    if (tid < D) outp[tid] = lds_part[tid] + lds_part[tid + 128];
}

// ---------------- Kernel B: pv[b,d] = sum_h tanh(q@Wq+bq)[b,d*64+h]*w_red[h] -
// Folds w_red into the GEMM epilogue: s@w_red is linear, so downstream only
// needs pv (B,D), never the 8 MB pq tensor.
// Grid: (d=0..127, mgroup=0..7). Block 256 = 4 waves; wave handles 8 rows,
// lane = h. Each thread: 8 accumulators over k=0..127.
__global__ __launch_bounds__(256) void pv_kernel(
    const float* __restrict__ q_emb, const float* __restrict__ Wq,
    const float* __restrict__ bq, const float* __restrict__ w_red,
    float* __restrict__ pv)
{
    __shared__ float qs[32 * 128];   // 16 KB: 32 q rows
    int dd  = blockIdx.x;            // 0..127  (the "d" of pq reshape)
    int m0  = blockIdx.y * 32;       // row group
    int tid = threadIdx.x;

    #pragma unroll
    for (int i = 0; i < 16; ++i) {
        int idx = i * 256 + tid;
        qs[idx] = q_emb[m0 * 128 + idx];
    }
    __syncthreads();

    int wave = tid >> 6;
    int h    = tid & 63;
    const float* wcol = Wq + dd * 64 + h;   // column d*64+h, stride 8192 over k

    float acc[8];
    #pragma unroll
    for (int mm = 0; mm < 8; ++mm) acc[mm] = 0.f;

    // k-loop by 4 so LDS reads are ds_read_b128 (wave-uniform broadcast)
    for (int k4 = 0; k4 < 32; ++k4) {
        float wv0 = wcol[(k4 * 4 + 0) * 8192];
        float wv1 = wcol[(k4 * 4 + 1) * 8192];
        float wv2 = wcol[(k4 * 4 + 2) * 8192];
        float wv3 = wcol[(k4 * 4 + 3) * 8192];
        #pragma unroll
        for (int mm = 0; mm < 8; ++mm) {
            const float4 q = ((const float4*)(qs + (wave * 8 + mm) * 128))[k4];
            acc[mm] += q.x * wv0 + q.y * wv1 + q.z * wv2 + q.w * wv3;
        }
    }

    float bqv = bq[dd * 64 + h];
    float wr  = w_red[h];
    #pragma unroll
    for (int mm = 0; mm < 8; ++mm) {
        float v = tanhf(acc[mm] + bqv) * wr;
        #pragma unroll
        for (int off = 32; off > 0; off >>= 1)
            v += __shfl_down(v, off, 64);
        if (h == 0) pv[(m0 + wave * 8 + mm) * 128 + dd] = v;
    }
}

// ---------------- Kernel C: review attention + output ------------------------
// r_score[b,r] = rev[b,r,:]·pv[b,:]; softmax over R; out = sum_r w_r rev[b,r,:]
// set 0: user (+ pf*q_emb -> personalized), set 1: item.
__global__ __launch_bounds__(256) void attn_kernel(
    const float* __restrict__ user_emb, const float* __restrict__ item_emb,
    const float* __restrict__ q_emb, const float* __restrict__ pv,
    const float* __restrict__ pf, float* __restrict__ out)
{
    __shared__ float rev[R * 129];
    __shared__ float pvl[D];
    __shared__ float sc[R];

    int b   = blockIdx.x;
    int set = blockIdx.y;
    const float* revg = (set == 0 ? user_emb : item_emb) + b * R * D;
    int tid = threadIdx.x;

    for (int idx = tid; idx < R * D; idx += 256)
        rev[(idx >> 7) * 129 + (idx & 127)] = revg[idx];
    if (tid < D) pvl[tid] = pv[b * D + tid];
    __syncthreads();

    if (tid < R) {
        float s = 0.f;
        const float* row = &rev[tid * 129];
        #pragma unroll 16
        for (int k = 0; k < D; ++k) s += row[k] * pvl[k];
        sc[tid] = s;
    }
    __syncthreads();

    float m = -1e30f;
    for (int r = 0; r < R; ++r) m = fmaxf(m, sc[r]);
    float sum = 0.f;
    for (int r = 0; r < R; ++r) sum += expf(sc[r] - m);
    float inv = 1.f / sum;

    if (tid < D) {
        float acc = 0.f;
        for (int r = 0; r < R; ++r)
            acc += expf(sc[r] - m) * inv * rev[r * 129 + tid];
        if (set == 0) {
            acc += pf[0] * q_emb[b * D + tid];
            out[b * D + tid] = acc;                 // personalized
        } else {
            out[NB * D + b * D + tid] = acc;        // item_entity
        }
    }
}

extern "C" void kernel_launch(void* const* d_in, const int* in_sizes, int n_in,
                              void* d_out, int out_size, void* d_ws, size_t ws_size,
                              hipStream_t stream) {
    const int*   user_w  = (const int*)d_in[0];
    const int*   item_w  = (const int*)d_in[1];
    const int*   query_w = (const int*)d_in[2];
    const float* emb     = (const float*)d_in[3];
    const float* w_self  = (const float*)d_in[4];
    const float* b_self  = (const float*)d_in[5];
    const float* Wq      = (const float*)d_in[6];
    const float* bq      = (const float*)d_in[7];
    const float* w_red   = (const float*)d_in[8];
    const float* pf      = (const float*)d_in[9];

    float* ws       = (float*)d_ws;
    float* user_emb = ws;                         // 5120*128
    float* item_emb = user_emb + NDOC_UI * D;     // 5120*128
    float* q_emb    = item_emb + NDOC_UI * D;     // 256*128
    float* pv       = q_emb    + NB * D;          // 256*128
    float* out      = (float*)d_out;

    doc_embed_kernel<<<2 * NDOC_UI + NB, 256, 0, stream>>>(
        user_w, item_w, query_w, emb, w_self, b_self, user_emb, item_emb, q_emb);
    pv_kernel<<<dim3(128, 8), 256, 0, stream>>>(q_emb, Wq, bq, w_red, pv);
    attn_kernel<<<dim3(NB, 2), 256, 0, stream>>>(user_emb, item_emb, q_emb, pv, pf, out);
}

// Round 2
// 220.693 us; speedup vs baseline: 1.3990x; 1.3990x over previous
//
#include <hip/hip_runtime.h>
#include <math.h>

#define D 128
#define H 64
#define W 100
#define R 20
#define NB 256
#define NDOC_UI (NB * R)   // 5120

// ---------------- Kernel A: tanh-self-attention doc embedding ----------------
// One block (256 threads = 8 row-groups of 32 lanes) per document.
// - gather: each 32-lane group loads one emb row as float4 (13 batched passes)
// - score: folded into staging via 32-lane shuffle reduction -> exp(tanh(.))
// - softmax denom: single wave-64 reduction (no max pass needed: tanh in (-1,1))
// - weighted sum: float2 per thread, 4 groups x 25 words, 1/sum in epilogue
__global__ __launch_bounds__(256) void doc_embed_kernel(
    const int* __restrict__ user_w, const int* __restrict__ item_w,
    const int* __restrict__ query_w,
    const float* __restrict__ emb, const float* __restrict__ w_self,
    const float* __restrict__ b_self,
    float* __restrict__ user_emb, float* __restrict__ item_emb,
    float* __restrict__ q_emb)
{
    __shared__ __align__(16) float lds_we[W * 128];   // 51200 B, unpadded
    __shared__ float  lds_e[W + 4];                   // exp(tanh(score))
    __shared__ int    lds_words[W + 4];
    __shared__ float2 lds_part[256];                  // 2 KB
    __shared__ float  lds_inv;

    int doc = blockIdx.x;
    const int* wp; float* outp;
    if (doc < NDOC_UI)          { wp = user_w  + doc * W;              outp = user_emb + doc * D; }
    else if (doc < 2*NDOC_UI)   { int t = doc - NDOC_UI;   wp = item_w  + t * W; outp = item_emb + t * D; }
    else                        { int t = doc - 2*NDOC_UI; wp = query_w + t * W; outp = q_emb    + t * D; }

    int tid    = threadIdx.x;
    int lane32 = tid & 31;
    int rowgrp = tid >> 5;     // 0..7

    if (tid < W) lds_words[tid] = wp[tid];
    float4 ws4 = ((const float4*)w_self)[lane32];
    float  bs  = b_self[0];
    __syncthreads();

    // Batch all gathers first (13 float4 loads in flight), then process.
    float4 v[13];
    #pragma unroll
    for (int i = 0; i < 13; ++i) {
        int w = i * 8 + rowgrp;
        if (w < W) {
            int word = lds_words[w];
            v[i] = ((const float4*)emb)[word * 32 + lane32];
        }
    }
    #pragma unroll
    for (int i = 0; i < 13; ++i) {
        int w = i * 8 + rowgrp;
        if (w < W) {
            ((float4*)lds_we)[w * 32 + lane32] = v[i];
            float p = v[i].x * ws4.x + v[i].y * ws4.y + v[i].z * ws4.z + v[i].w * ws4.w;
            p += __shfl_xor(p, 16, 64);
            p += __shfl_xor(p, 8, 64);
            p += __shfl_xor(p, 4, 64);
            p += __shfl_xor(p, 2, 64);
            p += __shfl_xor(p, 1, 64);
            if (lane32 == 0) lds_e[w] = expf(tanhf(p + bs));
        }
    }
    __syncthreads();

    // Wave 0 computes 1/sum while all waves proceed to the weighted sum.
    if (tid < 64) {
        float s = lds_e[tid] + ((tid + 64 < W) ? lds_e[tid + 64] : 0.f);
        s += __shfl_xor(s, 32, 64);
        s += __shfl_xor(s, 16, 64);
        s += __shfl_xor(s, 8, 64);
        s += __shfl_xor(s, 4, 64);
        s += __shfl_xor(s, 2, 64);
        s += __shfl_xor(s, 1, 64);
        if (tid == 0) lds_inv = 1.f / s;
    }

    // Weighted sum: group g (0..3) handles words g*25..g*25+24, float2 over d.
    int g = tid >> 6;          // wave id
    int p = tid & 63;          // d-pair index
    float2 acc = make_float2(0.f, 0.f);
    const float2* we2 = (const float2*)lds_we;
    for (int i = 0; i < 25; ++i) {
        int w = g * 25 + i;
        float e = lds_e[w];                 // wave-uniform broadcast
        float2 x = we2[w * 64 + p];
        acc.x += e * x.x;
        acc.y += e * x.y;
    }
    lds_part[tid] = acc;
    __syncthreads();

    if (tid < 64) {
        float2 r0 = lds_part[tid];
        float2 r1 = lds_part[64 + tid];
        float2 r2 = lds_part[128 + tid];
        float2 r3 = lds_part[192 + tid];
        float inv = lds_inv;
        float2 r;
        r.x = (r0.x + r1.x + r2.x + r3.x) * inv;
        r.y = (r0.y + r1.y + r2.y + r3.y) * inv;
        ((float2*)outp)[tid] = r;
    }
}

// ---------------- Kernel B: pv[b,d] = sum_h tanh(q@Wq+bq)[b,d*64+h]*w_red[h] -
// w_red folded into GEMM epilogue (linear), so the 8 MB pq tensor never exists.
// Grid (dd=0..127, mg=0..1). Block: 256 thr = 32 m-threads x 8 n-threads,
// register tile 4m x 8n. Full tiles staged in LDS (coalesced global reads):
// qs (128m x 128k, pad 132) + Wb (128k x 64n, pad 68) = 102 KB -> 1 block/CU.
__global__ __launch_bounds__(256) void pv_kernel(
    const float* __restrict__ q_emb, const float* __restrict__ Wq,
    const float* __restrict__ bq, const float* __restrict__ w_red,
    float* __restrict__ pv)
{
    __shared__ __align__(16) float qs[128 * 132];   // [m][k] pad 132
    __shared__ __align__(16) float Wb[128 * 68];    // [k][n] pad 68

    int dd  = blockIdx.x;          // 0..127
    int m0g = blockIdx.y * 128;    // row offset
    int tid = threadIdx.x;

    // Stage q tile: 8 passes, 16 threads/row x 16 float4/row (coalesced 512B/row)
    {
        int rrow = tid >> 4;       // 0..15
        int f4   = tid & 15;       // 0..15
        #pragma unroll
        for (int pass = 0; pass < 8; ++pass) {
            int m = pass * 16 + rrow;
            float4 vq = ((const float4*)q_emb)[(m0g + m) * 32 + f4];
            *(float4*)&qs[m * 132 + f4 * 4] = vq;
        }
        // Stage Wq tile: row k -> 64 consecutive floats at Wq[k*8192 + dd*64]
        #pragma unroll
        for (int pass = 0; pass < 8; ++pass) {
            int k = pass * 16 + rrow;
            float4 vw = ((const float4*)Wq)[k * 2048 + dd * 16 + f4];
            *(float4*)&Wb[k * 68 + f4 * 4] = vw;
        }
    }
    __syncthreads();

    int nthr = tid & 7;            // n0 = nthr*8
    int mthr = tid >> 3;           // m0 = mthr*4
    int n0 = nthr * 8;
    int m0 = mthr * 4;

    float acc[4][8];
    #pragma unroll
    for (int i = 0; i < 4; ++i)
        #pragma unroll
        for (int j = 0; j < 8; ++j) acc[i][j] = 0.f;

    for (int k = 0; k < 128; ++k) {
        float4 b0 = *(const float4*)&Wb[k * 68 + n0];
        float4 b1 = *(const float4*)&Wb[k * 68 + n0 + 4];
        float a0 = qs[(m0 + 0) * 132 + k];
        float a1 = qs[(m0 + 1) * 132 + k];
        float a2 = qs[(m0 + 2) * 132 + k];
        float a3 = qs[(m0 + 3) * 132 + k];
        float bv[8] = {b0.x, b0.y, b0.z, b0.w, b1.x, b1.y, b1.z, b1.w};
        float av[4] = {a0, a1, a2, a3};
        #pragma unroll
        for (int i = 0; i < 4; ++i)
            #pragma unroll
            for (int j = 0; j < 8; ++j)
                acc[i][j] += av[i] * bv[j];
    }

    // Epilogue: tanh(+bq)*w_red, reduce over the 8 n-threads (lane bits 0..2)
    float4 bqa = ((const float4*)bq)[dd * 16 + nthr * 2];
    float4 bqb = ((const float4*)bq)[dd * 16 + nthr * 2 + 1];
    float4 wra = ((const float4*)w_red)[nthr * 2];
    float4 wrb = ((const float4*)w_red)[nthr * 2 + 1];
    float bqv[8] = {bqa.x, bqa.y, bqa.z, bqa.w, bqb.x, bqb.y, bqb.z, bqb.w};
    float wrv[8] = {wra.x, wra.y, wra.z, wra.w, wrb.x, wrb.y, wrb.z, wrb.w};

    #pragma unroll
    for (int i = 0; i < 4; ++i) {
        float s = 0.f;
        #pragma unroll
        for (int j = 0; j < 8; ++j)
            s += tanhf(acc[i][j] + bqv[j]) * wrv[j];
        s += __shfl_xor(s, 1, 64);
        s += __shfl_xor(s, 2, 64);
        s += __shfl_xor(s, 4, 64);
        if (nthr == 0) pv[(m0g + m0 + i) * 128 + dd] = s;
    }
}

// ---------------- Kernel C: review attention + output ------------------------
__global__ __launch_bounds__(256) void attn_kernel(
    const float* __restrict__ user_emb, const float* __restrict__ item_emb,
    const float* __restrict__ q_emb, const float* __restrict__ pv,
    const float* __restrict__ pf, float* __restrict__ out)
{
    __shared__ float rev[R * 129];
    __shared__ float pvl[D];
    __shared__ float sc[R];

    int b   = blockIdx.x;
    int set = blockIdx.y;
    const float* revg = (set == 0 ? user_emb : item_emb) + b * R * D;
    int tid = threadIdx.x;

    for (int idx = tid; idx < R * D; idx += 256)
        rev[(idx >> 7) * 129 + (idx & 127)] = revg[idx];
    if (tid < D) pvl[tid] = pv[b * D + tid];
    __syncthreads();

    if (tid < R) {
        float s = 0.f;
        const float* row = &rev[tid * 129];
        #pragma unroll 16
        for (int k = 0; k < D; ++k) s += row[k] * pvl[k];
        sc[tid] = s;
    }
    __syncthreads();

    float m = -1e30f;
    for (int r = 0; r < R; ++r) m = fmaxf(m, sc[r]);
    float sum = 0.f;
    for (int r = 0; r < R; ++r) sum += expf(sc[r] - m);
    float inv = 1.f / sum;

    if (tid < D) {
        float acc = 0.f;
        for (int r = 0; r < R; ++r)
            acc += expf(sc[r] - m) * inv * rev[r * 129 + tid];
        if (set == 0) {
            acc += pf[0] * q_emb[b * D + tid];
            out[b * D + tid] = acc;                 // personalized
        } else {
            out[NB * D + b * D + tid] = acc;        // item_entity
        }
    }
}

extern "C" void kernel_launch(void* const* d_in, const int* in_sizes, int n_in,
                              void* d_out, int out_size, void* d_ws, size_t ws_size,
                              hipStream_t stream) {
    const int*   user_w  = (const int*)d_in[0];
    const int*   item_w  = (const int*)d_in[1];
    const int*   query_w = (const int*)d_in[2];
    const float* emb     = (const float*)d_in[3];
    const float* w_self  = (const float*)d_in[4];
    const float* b_self  = (const float*)d_in[5];
    const float* Wq      = (const float*)d_in[6];
    const float* bq      = (const float*)d_in[7];
    const float* w_red   = (const float*)d_in[8];
    const float* pf      = (const float*)d_in[9];

    float* ws       = (float*)d_ws;
    float* user_emb = ws;                         // 5120*128
    float* item_emb = user_emb + NDOC_UI * D;     // 5120*128
    float* q_emb    = item_emb + NDOC_UI * D;     // 256*128
    float* pv       = q_emb    + NB * D;          // 256*128
    float* out      = (float*)d_out;

    doc_embed_kernel<<<2 * NDOC_UI + NB, 256, 0, stream>>>(
        user_w, item_w, query_w, emb, w_self, b_self, user_emb, item_emb, q_emb);
    pv_kernel<<<dim3(128, 2), 256, 0, stream>>>(q_emb, Wq, bq, w_red, pv);
    attn_kernel<<<dim3(NB, 2), 256, 0, stream>>>(user_emb, item_emb, q_emb, pv, pf, out);
}

// Round 3
// 168.110 us; speedup vs baseline: 1.8367x; 1.3128x over previous
//
#include <hip/hip_runtime.h>
#include <math.h>

#define D 128
#define H 64
#define W 100
#define R 20
#define NB 256
#define NDOC_UI (NB * R)   // 5120

// ---------------- Kernel A: tanh-self-attention doc embedding ----------------
// One block (256 threads = 8 groups of 32 lanes) per document.
// Register-resident: each group gathers its 13 rows as float4 into VGPRs
// (13 loads in flight), computes score via 32-lane shuffle reduce, weight
// e=exp(tanh(.)) once per word, accumulates e*row in registers, and reduces
// the 8 group partials through a 4 KB LDS buffer. No 51 KB row staging ->
// ~5 KB LDS -> high occupancy for gather latency hiding.
__global__ __launch_bounds__(256) void doc_embed_kernel(
    const int* __restrict__ user_w, const int* __restrict__ item_w,
    const int* __restrict__ query_w,
    const float* __restrict__ emb, const float* __restrict__ w_self,
    const float* __restrict__ b_self,
    float* __restrict__ user_emb, float* __restrict__ item_emb,
    float* __restrict__ q_emb)
{
    __shared__ int   lds_words[W + 4];
    __shared__ float lds_esum[8];
    __shared__ __align__(16) float lds_part[8 * 128];   // 4 KB

    int doc = blockIdx.x;
    const int* wp; float* outp;
    if (doc < NDOC_UI)          { wp = user_w  + doc * W;              outp = user_emb + doc * D; }
    else if (doc < 2*NDOC_UI)   { int t = doc - NDOC_UI;   wp = item_w  + t * W; outp = item_emb + t * D; }
    else                        { int t = doc - 2*NDOC_UI; wp = query_w + t * W; outp = q_emb    + t * D; }

    int tid    = threadIdx.x;
    int lane32 = tid & 31;
    int g      = tid >> 5;     // group 0..7; group g owns words w = i*8+g

    if (tid < W) lds_words[tid] = wp[tid];
    float4 ws4 = ((const float4*)w_self)[lane32];
    float  bs  = b_self[0];
    __syncthreads();

    // Batched gather: up to 13 float4 loads in flight per thread.
    float4 v[13];
    #pragma unroll
    for (int i = 0; i < 13; ++i) {
        int w = i * 8 + g;
        if (w < W)
            v[i] = ((const float4*)emb)[(size_t)lds_words[w] * 32 + lane32];
    }

    // Per-word: score (shuffle-reduced dot), e = exp(tanh(.+b)), accumulate.
    float4 acc = make_float4(0.f, 0.f, 0.f, 0.f);
    float  esum = 0.f;
    #pragma unroll
    for (int i = 0; i < 13; ++i) {
        int w = i * 8 + g;               // wave-uniform predicate
        if (w < W) {
            float p = v[i].x * ws4.x + v[i].y * ws4.y + v[i].z * ws4.z + v[i].w * ws4.w;
            p += __shfl_xor(p, 16, 64);
            p += __shfl_xor(p, 8, 64);
            p += __shfl_xor(p, 4, 64);
            p += __shfl_xor(p, 2, 64);
            p += __shfl_xor(p, 1, 64);
            float e = expf(tanhf(p + bs));
            esum += e;
            acc.x += e * v[i].x;
            acc.y += e * v[i].y;
            acc.z += e * v[i].z;
            acc.w += e * v[i].w;
        }
    }
    *(float4*)&lds_part[g * 128 + lane32 * 4] = acc;
    if (lane32 == 0) lds_esum[g] = esum;
    __syncthreads();

    if (tid < 64) {
        float s = lds_esum[0] + lds_esum[1] + lds_esum[2] + lds_esum[3]
                + lds_esum[4] + lds_esum[5] + lds_esum[6] + lds_esum[7];
        float inv = 1.f / s;
        float2 o = make_float2(0.f, 0.f);
        #pragma unroll
        for (int gg = 0; gg < 8; ++gg) {
            float2 p2 = *(const float2*)&lds_part[gg * 128 + tid * 2];
            o.x += p2.x;
            o.y += p2.y;
        }
        o.x *= inv;
        o.y *= inv;
        ((float2*)outp)[tid] = o;
    }
}

// ---------------- Kernel B: pv[b,d] = sum_h tanh(q@Wq+bq)[b,d*64+h]*w_red[h] -
// w_red folded into GEMM epilogue (linear), so the 8 MB pq tensor never exists.
// Grid (dd=0..127, mg=0..3). Tiles: qs 64m x 128k (pad 132) + Wb 128k x 64n
// (pad 68) = 69 KB -> 2 blocks/CU (8 waves/CU) for k-loop latency hiding.
// Register tile 2m x 8n per thread (32 m-thr x 8 n-thr).
__global__ __launch_bounds__(256) void pv_kernel(
    const float* __restrict__ q_emb, const float* __restrict__ Wq,
    const float* __restrict__ bq, const float* __restrict__ w_red,
    float* __restrict__ pv)
{
    __shared__ __align__(16) float qs[64 * 132];    // 33.8 KB
    __shared__ __align__(16) float Wb[128 * 68];    // 34.8 KB

    int dd  = blockIdx.x;          // 0..127
    int m0g = blockIdx.y * 64;     // row offset
    int tid = threadIdx.x;

    {
        int rrow = tid >> 4;       // 0..15
        int f4   = tid & 15;       // 0..15
        #pragma unroll
        for (int pass = 0; pass < 4; ++pass) {
            int m = pass * 16 + rrow;
            float4 vq = ((const float4*)q_emb)[(m0g + m) * 32 + f4];
            *(float4*)&qs[m * 132 + f4 * 4] = vq;
        }
        #pragma unroll
        for (int pass = 0; pass < 8; ++pass) {
            int k = pass * 16 + rrow;
            float4 vw = ((const float4*)Wq)[k * 2048 + dd * 16 + f4];
            *(float4*)&Wb[k * 68 + f4 * 4] = vw;
        }
    }
    __syncthreads();

    int nthr = tid & 7;            // n0 = nthr*8
    int mthr = tid >> 3;           // m0 = mthr*2
    int n0 = nthr * 8;
    int m0 = mthr * 2;

    float acc[2][8];
    #pragma unroll
    for (int i = 0; i < 2; ++i)
        #pragma unroll
        for (int j = 0; j < 8; ++j) acc[i][j] = 0.f;

    for (int k = 0; k < 128; ++k) {
        float4 b0 = *(const float4*)&Wb[k * 68 + n0];
        float4 b1 = *(const float4*)&Wb[k * 68 + n0 + 4];
        float a0 = qs[(m0 + 0) * 132 + k];
        float a1 = qs[(m0 + 1) * 132 + k];
        float bv[8] = {b0.x, b0.y, b0.z, b0.w, b1.x, b1.y, b1.z, b1.w};
        #pragma unroll
        for (int j = 0; j < 8; ++j) {
            acc[0][j] += a0 * bv[j];
            acc[1][j] += a1 * bv[j];
        }
    }

    // Epilogue: tanh(+bq)*w_red, reduce over the 8 n-threads (lane bits 0..2)
    float4 bqa = ((const float4*)bq)[dd * 16 + nthr * 2];
    float4 bqb = ((const float4*)bq)[dd * 16 + nthr * 2 + 1];
    float4 wra = ((const float4*)w_red)[nthr * 2];
    float4 wrb = ((const float4*)w_red)[nthr * 2 + 1];
    float bqv[8] = {bqa.x, bqa.y, bqa.z, bqa.w, bqb.x, bqb.y, bqb.z, bqb.w};
    float wrv[8] = {wra.x, wra.y, wra.z, wra.w, wrb.x, wrb.y, wrb.z, wrb.w};

    #pragma unroll
    for (int i = 0; i < 2; ++i) {
        float s = 0.f;
        #pragma unroll
        for (int j = 0; j < 8; ++j)
            s += tanhf(acc[i][j] + bqv[j]) * wrv[j];
        s += __shfl_xor(s, 1, 64);
        s += __shfl_xor(s, 2, 64);
        s += __shfl_xor(s, 4, 64);
        if (nthr == 0) pv[(m0g + m0 + i) * 128 + dd] = s;
    }
}

// ---------------- Kernel C: review attention + output ------------------------
__global__ __launch_bounds__(256) void attn_kernel(
    const float* __restrict__ user_emb, const float* __restrict__ item_emb,
    const float* __restrict__ q_emb, const float* __restrict__ pv,
    const float* __restrict__ pf, float* __restrict__ out)
{
    __shared__ float rev[R * 129];
    __shared__ float pvl[D];
    __shared__ float sc[R];

    int b   = blockIdx.x;
    int set = blockIdx.y;
    const float* revg = (set == 0 ? user_emb : item_emb) + b * R * D;
    int tid = threadIdx.x;

    for (int idx = tid; idx < R * D; idx += 256)
        rev[(idx >> 7) * 129 + (idx & 127)] = revg[idx];
    if (tid < D) pvl[tid] = pv[b * D + tid];
    __syncthreads();

    if (tid < R) {
        float s = 0.f;
        const float* row = &rev[tid * 129];
        #pragma unroll 16
        for (int k = 0; k < D; ++k) s += row[k] * pvl[k];
        sc[tid] = s;
    }
    __syncthreads();

    float m = -1e30f;
    for (int r = 0; r < R; ++r) m = fmaxf(m, sc[r]);
    float sum = 0.f;
    for (int r = 0; r < R; ++r) sum += expf(sc[r] - m);
    float inv = 1.f / sum;

    if (tid < D) {
        float acc = 0.f;
        for (int r = 0; r < R; ++r)
            acc += expf(sc[r] - m) * inv * rev[r * 129 + tid];
        if (set == 0) {
            acc += pf[0] * q_emb[b * D + tid];
            out[b * D + tid] = acc;                 // personalized
        } else {
            out[NB * D + b * D + tid] = acc;        // item_entity
        }
    }
}

extern "C" void kernel_launch(void* const* d_in, const int* in_sizes, int n_in,
                              void* d_out, int out_size, void* d_ws, size_t ws_size,
                              hipStream_t stream) {
    const int*   user_w  = (const int*)d_in[0];
    const int*   item_w  = (const int*)d_in[1];
    const int*   query_w = (const int*)d_in[2];
    const float* emb     = (const float*)d_in[3];
    const float* w_self  = (const float*)d_in[4];
    const float* b_self  = (const float*)d_in[5];
    const float* Wq      = (const float*)d_in[6];
    const float* bq      = (const float*)d_in[7];
    const float* w_red   = (const float*)d_in[8];
    const float* pf      = (const float*)d_in[9];

    float* ws       = (float*)d_ws;
    float* user_emb = ws;                         // 5120*128
    float* item_emb = user_emb + NDOC_UI * D;     // 5120*128
    float* q_emb    = item_emb + NDOC_UI * D;     // 256*128
    float* pv       = q_emb    + NB * D;          // 256*128
    float* out      = (float*)d_out;

    doc_embed_kernel<<<2 * NDOC_UI + NB, 256, 0, stream>>>(
        user_w, item_w, query_w, emb, w_self, b_self, user_emb, item_emb, q_emb);
    pv_kernel<<<dim3(128, 4), 256, 0, stream>>>(q_emb, Wq, bq, w_red, pv);
    attn_kernel<<<dim3(NB, 2), 256, 0, stream>>>(user_emb, item_emb, q_emb, pv, pf, out);
}